// Round 3
// baseline (348.765 us; speedup 1.0000x reference)
//
#include <hip/hip_runtime.h>
#include <hip/hip_bf16.h>

constexpr int kB  = 16;
constexpr int kT  = 4096;
constexpr int kD  = 512;
constexpr int kC  = 10;
constexpr int kFW = 100;
constexpr int kKW = 2 * kFW + 1;   // 201
constexpr int kKP = 544;           // padded GEMM K: 512 (W_enc) + 10 (W_att) + 22 zeros
constexpr int kCW = 32;            // conv row width in bf16 (10 real + 22 zeros)

typedef __attribute__((ext_vector_type(8))) short short8_t;  // 8 bf16 (4 VGPRs)
typedef __attribute__((ext_vector_type(4))) float float4_t;  // MFMA acc

__device__ __forceinline__ float tanh_fast(float x) {
  float ax = fabsf(x);
  float z  = __expf(-2.0f * ax);
  float r  = (1.0f - z) / (1.0f + z);
  return copysignf(r, x);
}

__device__ __forceinline__ short f2bf(float x) {  // RNE f32->bf16 (scalar)
  unsigned u = __float_as_uint(x);
  u += 0x7fffu + ((u >> 16) & 1u);
  return (short)(u >> 16);
}

__device__ __forceinline__ unsigned pk2(float lo, float hi) {  // packed cvt
  __hip_bfloat162 h = __float22bfloat162_rn(make_float2(lo, hi));
  union { __hip_bfloat162 h2; unsigned u; } cv; cv.h2 = h; return cv.u;
}

__device__ __forceinline__ void glds16(const void* g, void* l) {
  __builtin_amdgcn_global_load_lds(
      (const __attribute__((address_space(1))) void*)g,
      (__attribute__((address_space(3))) void*)l, 16, 0, 0);
}

// bias[b,d] = b_enc[d] + sum_k query[b,k] * W_dec[d,k]
__global__ void dec_bias_kernel(const float* __restrict__ query,
                                const float* __restrict__ W_dec,
                                const float* __restrict__ b_enc,
                                float* __restrict__ bias) {
  int gw   = (blockIdx.x * blockDim.x + threadIdx.x) >> 6;
  int lane = threadIdx.x & 63;
  int b = gw >> 9;
  int d = gw & (kD - 1);
  const float* q = query + (size_t)b * kD;
  const float* w = W_dec + (size_t)d * kD;
  float s = 0.f;
#pragma unroll
  for (int k0 = 0; k0 < kD; k0 += 256) {
    float4 qa = *(const float4*)(q + k0 + lane * 4);
    float4 wa = *(const float4*)(w + k0 + lane * 4);
    s += qa.x * wa.x + qa.y * wa.y + qa.z * wa.z + qa.w * wa.w;
  }
#pragma unroll
  for (int off = 32; off > 0; off >>= 1) s += __shfl_down(s, off, 64);
  if (lane == 0) bias[gw] = b_enc[d] + s;
}

// Wbf[d][544] bf16 = [W_enc[d][0:512] | W_att[d][0:10] | zeros]
__global__ void pack_w_kernel(const float* __restrict__ W_enc,
                              const float* __restrict__ W_att,
                              short* __restrict__ Wbf) {
  int d = blockIdx.x;
  for (int c = threadIdx.x; c < kKP; c += 256) {
    float v = 0.f;
    if (c < kD)            v = W_enc[(size_t)d * kD + c];
    else if (c < kD + kC)  v = W_att[(size_t)d * kC + (c - kD)];
    Wbf[(size_t)d * kKP + c] = f2bf(v);
  }
}

// convbf[b][t][0:32] bf16: 10 conv channels + 22 zeros (one 64B row per t)
__global__ void conv_kernel(const float* __restrict__ att_prev,
                            const float* __restrict__ W_conv,
                            short* __restrict__ convbf) {
  __shared__ float ap[256 + 2 * kFW];
  __shared__ float wc[kC * kKW];
  int b   = blockIdx.y;
  int t0  = blockIdx.x * 256;
  int tid = threadIdx.x;
  for (int i = tid; i < kC * kKW; i += 256) wc[i] = W_conv[i];
  for (int i = tid; i < 256 + 2 * kFW; i += 256) {
    int p = t0 - kFW + i;
    ap[i] = (p >= 0 && p < kT) ? att_prev[(size_t)b * kT + p] : 0.f;
  }
  __syncthreads();
  float acc[kC];
#pragma unroll
  for (int c = 0; c < kC; ++c) acc[c] = 0.f;
  for (int j = 0; j < kKW; ++j) {
    float a = ap[tid + j];
#pragma unroll
    for (int c = 0; c < kC; ++c) acc[c] += a * wc[c * kKW + j];
  }
  unsigned ow[16];
#pragma unroll
  for (int i = 0; i < 5; ++i) ow[i] = pk2(acc[2 * i], acc[2 * i + 1]);
#pragma unroll
  for (int i = 5; i < 16; ++i) ow[i] = 0u;
  uint4* out = (uint4*)(convbf + ((size_t)b * kT + t0 + tid) * kCW);
  out[0] = make_uint4(ow[0], ow[1], ow[2], ow[3]);
  out[1] = make_uint4(ow[4], ow[5], ow[6], ow[7]);
  out[2] = make_uint4(ow[8], ow[9], ow[10], ow[11]);
  out[3] = make_uint4(ow[12], ow[13], ow[14], ow[15]);
}

// e_kernel: bf16 MFMA GEMM (128x128 tile, K=544) + fused tanh/wg epilogue.
// XOR-swizzled LDS (chunk kq stored at kq ^ ((row>>1)&3)) -> conflict-free
// b128 staging writes, glds deposits, and frag reads.
constexpr int BM = 128, BN = 128, BK = 32;

__global__ __launch_bounds__(256) void e_kernel(
    const float* __restrict__ value, const short* __restrict__ convbf,
    const short* __restrict__ Wbf, const float* __restrict__ bias,
    const float* __restrict__ w_g, const int* __restrict__ lens,
    float* __restrict__ e_part) {
  __shared__ short As[BM * BK];   // 8 KB, chunk-swizzled
  __shared__ short Bs[BN * BK];   // 8 KB, chunk-swizzled

  int tid = threadIdx.x;
  // XCD swizzle: 4 n-blocks of one m-tile adjacent on the same XCD
  int L    = blockIdx.x;
  int xcd  = L & 7;
  int slot = L >> 3;
  int bn   = slot & 3;                 // 4 n-blocks (N=512)
  int mt   = xcd * 64 + (slot >> 2);   // 512 m-tiles
  int b  = mt >> 5;
  int t0 = (mt & 31) * BM;
  if (t0 >= lens[b]) return;           // masked tile: partials never read
  int n0 = bn * BN;

  int w    = tid >> 6;
  int lane = tid & 63;
  int nl   = lane & 15;
  int quad = lane >> 4;
  int wm = w >> 1, wn = w & 1;

  // ---- A staging (value fp32 -> bf16): thread -> (row srow, k-half skh)
  int srow = tid >> 1, skh = tid & 1;
  int ga = (srow >> 1) & 3;
  const float* aptr = value + ((size_t)(b * kT + t0) + srow) * kD + skh * 16;
  short* aw0 = &As[((srow << 2) + ((skh * 2)     ^ ga)) * 8];
  short* aw1 = &As[((srow << 2) + ((skh * 2 + 1) ^ ga)) * 8];

  // ---- B staging via glds: lane l deposits chunk l; pick source k-part so
  // the deposit lands swizzled.
  int kps = (lane & 3) ^ ((lane >> 3) & 3);
  const short* bsrc0 = Wbf + (size_t)(n0 + w * 32 + (lane >> 2)) * kKP + kps * 8;
  const short* bsrc1 = bsrc0 + (size_t)16 * kKP;
  short* bdst0 = &Bs[(w * 32) * BK];
  short* bdst1 = &Bs[(w * 32 + 16) * BK];

  // ---- last K-step: A from convbf via glds (rows already bf16, 22 zeros)
  const short* csrc0 = convbf + ((size_t)(b * kT + t0) + w * 32 + (lane >> 2)) * kCW + kps * 8;
  const short* csrc1 = csrc0 + (size_t)16 * kCW;

  // ---- frag read bases (swizzle folds to lane-constant: g = (nl>>1)&3)
  int swz = quad ^ ((nl >> 1) & 3);
  const short8_t* ard = (const short8_t*)&As[(((wm * 64 + nl) << 2) + swz) * 8];
  const short8_t* brd = (const short8_t*)&Bs[(((wn * 64 + nl) << 2) + swz) * 8];

  float4_t acc[4][4] = {};

  // preload A(0)
  float4 pf0 = *(const float4*)(aptr);
  float4 pf1 = *(const float4*)(aptr + 4);
  float4 pf2 = *(const float4*)(aptr + 8);
  float4 pf3 = *(const float4*)(aptr + 12);

  for (int kk = 0; kk < 17; ++kk) {
    __syncthreads();                      // prior frag reads done; LDS writable
    glds16(bsrc0 + kk * BK, bdst0);
    glds16(bsrc1 + kk * BK, bdst1);
    if (kk < 16) {
      union { short8_t s8; unsigned u[4]; } c0, c1;
      c0.u[0] = pk2(pf0.x, pf0.y); c0.u[1] = pk2(pf0.z, pf0.w);
      c0.u[2] = pk2(pf1.x, pf1.y); c0.u[3] = pk2(pf1.z, pf1.w);
      c1.u[0] = pk2(pf2.x, pf2.y); c1.u[1] = pk2(pf2.z, pf2.w);
      c1.u[2] = pk2(pf3.x, pf3.y); c1.u[3] = pk2(pf3.z, pf3.w);
      *(short8_t*)aw0 = c0.s8;
      *(short8_t*)aw1 = c1.s8;
    } else {
      glds16(csrc0, (void*)&As[(w * 32) * BK]);
      glds16(csrc1, (void*)&As[(w * 32 + 16) * BK]);
    }
    __syncthreads();                      // drains glds + ds_write
    if (kk < 15) {                        // prefetch overlaps MFMA below
      const float* np = aptr + (kk + 1) * BK;
      pf0 = *(const float4*)(np);
      pf1 = *(const float4*)(np + 4);
      pf2 = *(const float4*)(np + 8);
      pf3 = *(const float4*)(np + 12);
    }
    short8_t a_frag[4], b_frag[4];
#pragma unroll
    for (int i = 0; i < 4; ++i) a_frag[i] = ard[i * 64];
#pragma unroll
    for (int j = 0; j < 4; ++j) b_frag[j] = brd[j * 64];
#pragma unroll
    for (int i = 0; i < 4; ++i)
#pragma unroll
      for (int j = 0; j < 4; ++j)
        acc[i][j] = __builtin_amdgcn_mfma_f32_16x16x32_bf16(
            a_frag[i], b_frag[j], acc[i][j], 0, 0, 0);
  }

  // epilogue: partial e[t] = sum_d wg[d]*tanh(acc + bias[b,d]); 8 partials/(b,t)
  float bias_r[4], wg_r[4];
#pragma unroll
  for (int j = 0; j < 4; ++j) {
    int d = n0 + wn * 64 + j * 16 + nl;
    bias_r[j] = bias[b * kD + d];
    wg_r[j]   = w_g[d];
  }
  int p = wn * 4 + bn;
  float* ep = e_part + ((size_t)p * kB + b) * kT + t0 + wm * 64;
#pragma unroll
  for (int i = 0; i < 4; ++i) {
#pragma unroll
    for (int r = 0; r < 4; ++r) {
      float s = 0.f;
#pragma unroll
      for (int j = 0; j < 4; ++j)
        s += wg_r[j] * tanh_fast(acc[i][j][r] + bias_r[j]);
      s += __shfl_xor(s, 1, 64);
      s += __shfl_xor(s, 2, 64);
      s += __shfl_xor(s, 4, 64);
      s += __shfl_xor(s, 8, 64);
      if (nl == 0) ep[i * 16 + quad * 4 + r] = s;
    }
  }
}

// masked, sharpened softmax; combines the 8 e-partials through LDS
__global__ void softmax_kernel(const float* __restrict__ e_part,
                               const int* __restrict__ lens,
                               float* __restrict__ att) {
  __shared__ float eb[kT];           // 16 KB
  __shared__ float sred[256];
  int b = blockIdx.x, tid = threadIdx.x;
  int len = lens[b];
  const float* ep = e_part + (size_t)b * kT;
  float m = -3.0e38f;
  for (int t = tid; t < len; t += 256) {
    float s = 0.f;
#pragma unroll
    for (int p = 0; p < 8; ++p) s += ep[(size_t)p * kB * kT + t];
    eb[t] = s;
    m = fmaxf(m, s);
  }
  sred[tid] = m; __syncthreads();
  for (int s = 128; s > 0; s >>= 1) {
    if (tid < s) sred[tid] = fmaxf(sred[tid], sred[tid + s]);
    __syncthreads();
  }
  m = sred[0]; __syncthreads();
  float sum = 0.f;
  for (int t = tid; t < len; t += 256) sum += __expf(2.0f * (eb[t] - m));
  sred[tid] = sum; __syncthreads();
  for (int s = 128; s > 0; s >>= 1) {
    if (tid < s) sred[tid] += sred[tid + s];
    __syncthreads();
  }
  float inv = 1.0f / sred[0];
  for (int t = tid; t < kT; t += 256)
    att[(size_t)b * kT + t] = (t < len) ? __expf(2.0f * (eb[t] - m)) * inv : 0.0f;
}

// context[b,d] = sum_t value[b,t,d]*att[b,t]
__global__ void context_kernel(const float* __restrict__ value,
                               const float* __restrict__ att,
                               const int* __restrict__ lens,
                               float* __restrict__ ctx) {
  int b = blockIdx.y;
  int len = lens[b];
  int t0 = blockIdx.x * 128;
  if (t0 >= len) return;
  int tid = threadIdx.x;
  int d4 = (tid & 127) * 4;
  int th = tid >> 7;
  int tb = t0 + th * 64;
  int tmax = min(64, len - tb);
  const float* ap = att + (size_t)b * kT + tb;
  const float* vp = value + ((size_t)(b * kT) + tb) * kD + d4;
  float4 a = {0.f, 0.f, 0.f, 0.f};
#pragma unroll 4
  for (int t = 0; t < tmax; ++t) {
    float wt = ap[t];
    float4 v = *(const float4*)(vp + (size_t)t * kD);
    a.x += wt * v.x; a.y += wt * v.y; a.z += wt * v.z; a.w += wt * v.w;
  }
  if (tmax > 0) {
    atomicAdd(&ctx[b * kD + d4],     a.x);
    atomicAdd(&ctx[b * kD + d4 + 1], a.y);
    atomicAdd(&ctx[b * kD + d4 + 2], a.z);
    atomicAdd(&ctx[b * kD + d4 + 3], a.w);
  }
}

extern "C" void kernel_launch(void* const* d_in, const int* in_sizes, int n_in,
                              void* d_out, int out_size, void* d_ws, size_t ws_size,
                              hipStream_t stream) {
  const float* value    = (const float*)d_in[0];
  const float* query    = (const float*)d_in[1];
  const int*   lens     = (const int*)  d_in[2];
  const float* att_prev = (const float*)d_in[3];
  const float* W_enc    = (const float*)d_in[4];
  const float* b_enc    = (const float*)d_in[5];
  const float* W_dec    = (const float*)d_in[6];
  const float* W_att    = (const float*)d_in[7];
  const float* W_conv   = (const float*)d_in[8];
  const float* w_g      = (const float*)d_in[9];
  // d_in[10] = b_g : unused (softmax shift-invariant)

  float* ws     = (float*)d_ws;
  float* e_part = ws;                                      // 8*kB*kT fp32 (2 MB)
  short* convbf = (short*)(ws + (size_t)8 * kB * kT);      // kB*kT*32 bf16 (4 MB)
  float* bias   = (float*)(convbf + (size_t)kB * kT * kCW);// kB*kD (32 KB)
  short* Wbf    = (short*)(bias + (size_t)kB * kD);        // kD*kKP bf16 (557 KB)
  float* ctx = (float*)d_out;
  float* att = ctx + (size_t)kB * kD;

  hipMemsetAsync(ctx, 0, (size_t)kB * kD * sizeof(float), stream);

  dec_bias_kernel<<<kB * kD / 4, 256, 0, stream>>>(query, W_dec, b_enc, bias);
  pack_w_kernel<<<kD, 256, 0, stream>>>(W_enc, W_att, Wbf);
  conv_kernel<<<dim3(kT / 256, kB), 256, 0, stream>>>(att_prev, W_conv, convbf);
  e_kernel<<<2048, 256, 0, stream>>>(value, convbf, Wbf, bias, w_g, lens, e_part);
  softmax_kernel<<<kB, 256, 0, stream>>>(e_part, lens, att);
  context_kernel<<<dim3(kT / 128, kB), 256, 0, stream>>>(value, att, lens, ctx);
}

// Round 4
// 325.469 us; speedup vs baseline: 1.0716x; 1.0716x over previous
//
#include <hip/hip_runtime.h>
#include <hip/hip_bf16.h>

constexpr int kB  = 16;
constexpr int kT  = 4096;
constexpr int kD  = 512;
constexpr int kC  = 10;
constexpr int kFW = 100;
constexpr int kKW = 2 * kFW + 1;   // 201
constexpr int kKP = 544;           // GEMM K: 512 (W_enc) + 10 (W_att) + 22 zeros

typedef __attribute__((ext_vector_type(8))) short short8_t;  // 8 bf16 (4 VGPRs)
typedef __attribute__((ext_vector_type(4))) float float4_t;  // MFMA acc

__device__ __forceinline__ float tanh_fast(float x) {
  float ax = fabsf(x);
  float z  = __expf(-2.0f * ax);
  float r  = (1.0f - z) / (1.0f + z);
  return copysignf(r, x);
}

__device__ __forceinline__ short f2bf(float x) {  // RNE f32->bf16 (scalar)
  unsigned u = __float_as_uint(x);
  u += 0x7fffu + ((u >> 16) & 1u);
  return (short)(u >> 16);
}

__device__ __forceinline__ unsigned pk2(float lo, float hi) {  // packed cvt
  __hip_bfloat162 h = __float22bfloat162_rn(make_float2(lo, hi));
  union { __hip_bfloat162 h2; unsigned u; } cv; cv.h2 = h; return cv.u;
}

__device__ __forceinline__ float bf2f(short s) {
  return __uint_as_float(((unsigned)(unsigned short)s) << 16);
}

__device__ __forceinline__ void glds16(const void* g, void* l) {
  __builtin_amdgcn_global_load_lds(
      (const __attribute__((address_space(1))) void*)g,
      (__attribute__((address_space(3))) void*)l, 16, 0, 0);
}

// bias[b,d] = b_enc[d] + sum_k query[b,k] * W_dec[d,k]
__global__ void dec_bias_kernel(const float* __restrict__ query,
                                const float* __restrict__ W_dec,
                                const float* __restrict__ b_enc,
                                float* __restrict__ bias) {
  int gw   = (blockIdx.x * blockDim.x + threadIdx.x) >> 6;
  int lane = threadIdx.x & 63;
  int b = gw >> 9;
  int d = gw & (kD - 1);
  const float* q = query + (size_t)b * kD;
  const float* w = W_dec + (size_t)d * kD;
  float s = 0.f;
#pragma unroll
  for (int k0 = 0; k0 < kD; k0 += 256) {
    float4 qa = *(const float4*)(q + k0 + lane * 4);
    float4 wa = *(const float4*)(w + k0 + lane * 4);
    s += qa.x * wa.x + qa.y * wa.y + qa.z * wa.z + qa.w * wa.w;
  }
#pragma unroll
  for (int off = 32; off > 0; off >>= 1) s += __shfl_down(s, off, 64);
  if (lane == 0) bias[gw] = b_enc[d] + s;
}

// Wbf[d][544] bf16 = [W_enc[d][0:512] | W_att[d][0:10] | zeros]
__global__ void pack_w_kernel(const float* __restrict__ W_enc,
                              const float* __restrict__ W_att,
                              short* __restrict__ Wbf) {
  int d = blockIdx.x;
  for (int c = threadIdx.x; c < kKP; c += 256) {
    float v = 0.f;
    if (c < kD)            v = W_enc[(size_t)d * kD + c];
    else if (c < kD + kC)  v = W_att[(size_t)d * kC + (c - kD)];
    Wbf[(size_t)d * kKP + c] = f2bf(v);
  }
}

// Abf[b][t][0:512] = bf16(value[b][t][:]) — streaming convert, 64 t-rows/block
__global__ void convert_kernel(const float* __restrict__ value,
                               const int* __restrict__ lens,
                               short* __restrict__ Abf) {
  int b  = blockIdx.y;
  int t0 = blockIdx.x * 64;
  if (t0 >= lens[b]) return;   // fully-masked chunk: rows never read validly
  int tid = threadIdx.x;
  const float* src = value + ((size_t)b * kT + t0) * kD;
  short* dst = Abf + ((size_t)b * kT + t0) * kKP;
#pragma unroll
  for (int i = 0; i < 16; ++i) {
    int c = tid + i * 256;             // chunk 0..4095 (64 rows x 64 chunks)
    int row = c >> 6, col = (c & 63) * 8;
    float4 f0 = *(const float4*)(src + (size_t)row * kD + col);
    float4 f1 = *(const float4*)(src + (size_t)row * kD + col + 4);
    uint4 o;
    o.x = pk2(f0.x, f0.y); o.y = pk2(f0.z, f0.w);
    o.z = pk2(f1.x, f1.y); o.w = pk2(f1.z, f1.w);
    *(uint4*)(dst + (size_t)row * kKP + col) = o;
  }
}

// conv channels -> Abf[b][t][512:544] bf16 (10 real + 22 zeros)
__global__ void conv_kernel(const float* __restrict__ att_prev,
                            const float* __restrict__ W_conv,
                            short* __restrict__ Abf) {
  __shared__ float ap[256 + 2 * kFW];
  __shared__ float wc[kC * kKW];
  int b   = blockIdx.y;
  int t0  = blockIdx.x * 256;
  int tid = threadIdx.x;
  for (int i = tid; i < kC * kKW; i += 256) wc[i] = W_conv[i];
  for (int i = tid; i < 256 + 2 * kFW; i += 256) {
    int p = t0 - kFW + i;
    ap[i] = (p >= 0 && p < kT) ? att_prev[(size_t)b * kT + p] : 0.f;
  }
  __syncthreads();
  float acc[kC];
#pragma unroll
  for (int c = 0; c < kC; ++c) acc[c] = 0.f;
  for (int j = 0; j < kKW; ++j) {
    float a = ap[tid + j];
#pragma unroll
    for (int c = 0; c < kC; ++c) acc[c] += a * wc[c * kKW + j];
  }
  unsigned ow[16];
#pragma unroll
  for (int i = 0; i < 5; ++i) ow[i] = pk2(acc[2 * i], acc[2 * i + 1]);
#pragma unroll
  for (int i = 5; i < 16; ++i) ow[i] = 0u;
  uint4* out = (uint4*)(Abf + ((size_t)b * kT + t0 + tid) * kKP + kD);
  out[0] = make_uint4(ow[0], ow[1], ow[2], ow[3]);
  out[1] = make_uint4(ow[4], ow[5], ow[6], ow[7]);
  out[2] = make_uint4(ow[8], ow[9], ow[10], ow[11]);
  out[3] = make_uint4(ow[12], ow[13], ow[14], ow[15]);
}

// e_kernel: pure bf16 MFMA GEMM (128x128, K=544), all staging via
// global_load_lds with XOR chunk-swizzle (R3-verified conflict-free).
constexpr int BM = 128, BN = 128, BK = 32;

__global__ __launch_bounds__(256) void e_kernel(
    const short* __restrict__ Abf, const short* __restrict__ Wbf,
    const float* __restrict__ bias, const float* __restrict__ w_g,
    const int* __restrict__ lens, float* __restrict__ e_part) {
  __shared__ short As[BM * BK];   // 8 KB, chunk-swizzled
  __shared__ short Bs[BN * BK];   // 8 KB, chunk-swizzled

  int tid = threadIdx.x;
  // XCD swizzle: the 4 n-blocks of one m-tile land on the same XCD
  int L    = blockIdx.x;
  int xcd  = L & 7;
  int slot = L >> 3;
  int bn   = slot & 3;
  int mt   = xcd * 64 + (slot >> 2);
  int b  = mt >> 5;
  int t0 = (mt & 31) * BM;
  if (t0 >= lens[b]) return;           // masked tile: partials never read
  int n0 = bn * BN;

  int w    = tid >> 6;
  int lane = tid & 63;
  int nl   = lane & 15;
  int quad = lane >> 4;
  int wm = w >> 1, wn = w & 1;

  // staging: lane picks swizzled source k-chunk so glds deposit lands swizzled
  int kps = (lane & 3) ^ ((lane >> 3) & 3);
  const short* asrc0 = Abf + ((size_t)(b * kT + t0) + w * 32 + (lane >> 2)) * kKP + kps * 8;
  const short* asrc1 = asrc0 + (size_t)16 * kKP;
  short* adst0 = &As[(w * 32) * BK];
  short* adst1 = &As[(w * 32 + 16) * BK];
  const short* bsrc0 = Wbf + (size_t)(n0 + w * 32 + (lane >> 2)) * kKP + kps * 8;
  const short* bsrc1 = bsrc0 + (size_t)16 * kKP;
  short* bdst0 = &Bs[(w * 32) * BK];
  short* bdst1 = &Bs[(w * 32 + 16) * BK];

  // frag read bases (swizzle folds to lane-constant)
  int swz = quad ^ ((nl >> 1) & 3);
  const short8_t* ard = (const short8_t*)&As[(((wm * 64 + nl) << 2) + swz) * 8];
  const short8_t* brd = (const short8_t*)&Bs[(((wn * 64 + nl) << 2) + swz) * 8];

  float4_t acc[4][4] = {};

  for (int kk = 0; kk < 17; ++kk) {
    int ko = kk * BK;
    __syncthreads();                   // prior frag reads done; LDS writable
    glds16(asrc0 + ko, adst0);
    glds16(asrc1 + ko, adst1);
    glds16(bsrc0 + ko, bdst0);
    glds16(bsrc1 + ko, bdst1);
    __syncthreads();                   // drains glds deposits
    short8_t a_frag[4], b_frag[4];
#pragma unroll
    for (int i = 0; i < 4; ++i) a_frag[i] = ard[i * 64];
#pragma unroll
    for (int j = 0; j < 4; ++j) b_frag[j] = brd[j * 64];
#pragma unroll
    for (int i = 0; i < 4; ++i)
#pragma unroll
      for (int j = 0; j < 4; ++j)
        acc[i][j] = __builtin_amdgcn_mfma_f32_16x16x32_bf16(
            a_frag[i], b_frag[j], acc[i][j], 0, 0, 0);
  }

  // epilogue: partial e[t] = sum_d wg[d]*tanh(acc + bias[b,d]); 8 partials/(b,t)
  float bias_r[4], wg_r[4];
#pragma unroll
  for (int j = 0; j < 4; ++j) {
    int d = n0 + wn * 64 + j * 16 + nl;
    bias_r[j] = bias[b * kD + d];
    wg_r[j]   = w_g[d];
  }
  int p = wn * 4 + bn;
  float* ep = e_part + ((size_t)p * kB + b) * kT + t0 + wm * 64;
#pragma unroll
  for (int i = 0; i < 4; ++i) {
#pragma unroll
    for (int r = 0; r < 4; ++r) {
      float s = 0.f;
#pragma unroll
      for (int j = 0; j < 4; ++j)
        s += wg_r[j] * tanh_fast(acc[i][j][r] + bias_r[j]);
      s += __shfl_xor(s, 1, 64);
      s += __shfl_xor(s, 2, 64);
      s += __shfl_xor(s, 4, 64);
      s += __shfl_xor(s, 8, 64);
      if (nl == 0) ep[i * 16 + quad * 4 + r] = s;
    }
  }
}

// masked, sharpened softmax; combines the 8 e-partials through LDS
__global__ void softmax_kernel(const float* __restrict__ e_part,
                               const int* __restrict__ lens,
                               float* __restrict__ att) {
  __shared__ float eb[kT];
  __shared__ float sred[256];
  int b = blockIdx.x, tid = threadIdx.x;
  int len = lens[b];
  const float* ep = e_part + (size_t)b * kT;
  float m = -3.0e38f;
  for (int t = tid; t < len; t += 256) {
    float s = 0.f;
#pragma unroll
    for (int p = 0; p < 8; ++p) s += ep[(size_t)p * kB * kT + t];
    eb[t] = s;
    m = fmaxf(m, s);
  }
  sred[tid] = m; __syncthreads();
  for (int s = 128; s > 0; s >>= 1) {
    if (tid < s) sred[tid] = fmaxf(sred[tid], sred[tid + s]);
    __syncthreads();
  }
  m = sred[0]; __syncthreads();
  float sum = 0.f;
  for (int t = tid; t < len; t += 256) sum += __expf(2.0f * (eb[t] - m));
  sred[tid] = sum; __syncthreads();
  for (int s = 128; s > 0; s >>= 1) {
    if (tid < s) sred[tid] += sred[tid + s];
    __syncthreads();
  }
  float inv = 1.0f / sred[0];
  for (int t = tid; t < kT; t += 256)
    att[(size_t)b * kT + t] = (t < len) ? __expf(2.0f * (eb[t] - m)) * inv : 0.0f;
}

// context[b,d] = sum_t bf16(value)[b,t,d]*att[b,t]  (reads Abf: half traffic)
__global__ void context_kernel(const short* __restrict__ Abf,
                               const float* __restrict__ att,
                               const int* __restrict__ lens,
                               float* __restrict__ ctx) {
  __shared__ float red[4][kD];
  int b = blockIdx.y;
  int len = lens[b];
  int t0 = blockIdx.x * 128;
  if (t0 >= len) return;
  int w = threadIdx.x >> 6, lane = threadIdx.x & 63;
  int tb = t0 + w * 32;
  int tmax = min(32, len - tb);        // may be <=0 for straddling tail
  float a[8] = {0.f, 0.f, 0.f, 0.f, 0.f, 0.f, 0.f, 0.f};
  const short* vp = Abf + ((size_t)b * kT + tb) * kKP + lane * 8;
  const float* ap = att + (size_t)b * kT + tb;
  for (int t = 0; t < tmax; ++t) {
    float wt = ap[t];
    short8_t v = *(const short8_t*)(vp + (size_t)t * kKP);
#pragma unroll
    for (int i = 0; i < 8; ++i) a[i] += wt * bf2f(v[i]);
  }
#pragma unroll
  for (int i = 0; i < 8; ++i) red[w][lane * 8 + i] = a[i];
  __syncthreads();
  int tid = threadIdx.x;
  for (int col = tid; col < kD; col += 256) {
    float s = red[0][col] + red[1][col] + red[2][col] + red[3][col];
    atomicAdd(&ctx[b * kD + col], s);
  }
}

extern "C" void kernel_launch(void* const* d_in, const int* in_sizes, int n_in,
                              void* d_out, int out_size, void* d_ws, size_t ws_size,
                              hipStream_t stream) {
  const float* value    = (const float*)d_in[0];
  const float* query    = (const float*)d_in[1];
  const int*   lens     = (const int*)  d_in[2];
  const float* att_prev = (const float*)d_in[3];
  const float* W_enc    = (const float*)d_in[4];
  const float* b_enc    = (const float*)d_in[5];
  const float* W_dec    = (const float*)d_in[6];
  const float* W_att    = (const float*)d_in[7];
  const float* W_conv   = (const float*)d_in[8];
  const float* w_g      = (const float*)d_in[9];
  // d_in[10] = b_g : unused (softmax shift-invariant)

  float* ws     = (float*)d_ws;
  float* e_part = ws;                                      // 8*kB*kT fp32 (2 MB)
  float* bias   = e_part + (size_t)8 * kB * kT;            // kB*kD (32 KB)
  short* Wbf    = (short*)(bias + (size_t)kB * kD);        // kD*kKP bf16 (557 KB)
  short* Abf    = Wbf + (size_t)kD * kKP;                  // kB*kT*kKP bf16 (71.3 MB)
  float* ctx = (float*)d_out;
  float* att = ctx + (size_t)kB * kD;

  hipMemsetAsync(ctx, 0, (size_t)kB * kD * sizeof(float), stream);

  dec_bias_kernel<<<kB * kD / 4, 256, 0, stream>>>(query, W_dec, b_enc, bias);
  pack_w_kernel<<<kD, 256, 0, stream>>>(W_enc, W_att, Wbf);
  convert_kernel<<<dim3(kT / 64, kB), 256, 0, stream>>>(value, lens, Abf);
  conv_kernel<<<dim3(kT / 256, kB), 256, 0, stream>>>(att_prev, W_conv, Abf);
  e_kernel<<<2048, 256, 0, stream>>>(Abf, Wbf, bias, w_g, lens, e_part);
  softmax_kernel<<<kB, 256, 0, stream>>>(e_part, lens, att);
  context_kernel<<<dim3(kT / 128, kB), 256, 0, stream>>>(Abf, att, lens, ctx);
}

// Round 5
// 295.622 us; speedup vs baseline: 1.1798x; 1.1010x over previous
//
#include <hip/hip_runtime.h>
#include <hip/hip_bf16.h>

constexpr int kB  = 16;
constexpr int kT  = 4096;
constexpr int kD  = 512;
constexpr int kC  = 10;
constexpr int kFW = 100;
constexpr int kKW = 2 * kFW + 1;   // 201
constexpr int kKP = 576;           // GEMM K: 512 (W_enc) + 10 (W_att) + 54 zeros (9x64)

typedef __attribute__((ext_vector_type(8))) short short8_t;  // 8 bf16 (4 VGPRs)
typedef __attribute__((ext_vector_type(4))) float float4_t;  // MFMA acc

__device__ __forceinline__ float tanh_fast(float x) {
  float ax = fabsf(x);
  float z  = __expf(-2.0f * ax);
  float r  = (1.0f - z) / (1.0f + z);
  return copysignf(r, x);
}

__device__ __forceinline__ short f2bf(float x) {  // RNE f32->bf16 (scalar)
  unsigned u = __float_as_uint(x);
  u += 0x7fffu + ((u >> 16) & 1u);
  return (short)(u >> 16);
}

__device__ __forceinline__ unsigned pk2(float lo, float hi) {  // packed cvt
  __hip_bfloat162 h = __float22bfloat162_rn(make_float2(lo, hi));
  union { __hip_bfloat162 h2; unsigned u; } cv; cv.h2 = h; return cv.u;
}

__device__ __forceinline__ float bf2f(short s) {
  return __uint_as_float(((unsigned)(unsigned short)s) << 16);
}

__device__ __forceinline__ void glds16(const void* g, void* l) {
  __builtin_amdgcn_global_load_lds(
      (const __attribute__((address_space(1))) void*)g,
      (__attribute__((address_space(3))) void*)l, 16, 0, 0);
}

// ---- fused prep: dec_bias | pack_w | conv | convert (independent block ranges)
__global__ __launch_bounds__(256) void prep_kernel(
    const float* __restrict__ query, const float* __restrict__ W_dec,
    const float* __restrict__ b_enc, float* __restrict__ bias,
    const float* __restrict__ W_enc, const float* __restrict__ W_att,
    short* __restrict__ Wbf,
    const float* __restrict__ att_prev, const float* __restrict__ W_conv,
    const float* __restrict__ value, const int* __restrict__ lens,
    short* __restrict__ Abf) {
  __shared__ float ap[256 + 2 * kFW];
  __shared__ float wc[kC * kKW];
  int blk = blockIdx.x;
  int tid = threadIdx.x;

  if (blk < 2048) {
    // dec_bias: bias[b,d] = b_enc[d] + query[b,:] . W_dec[d,:]
    int gw   = (blk * 256 + tid) >> 6;
    int lane = tid & 63;
    int b = gw >> 9, d = gw & (kD - 1);
    const float* q = query + (size_t)b * kD;
    const float* w = W_dec + (size_t)d * kD;
    float s = 0.f;
#pragma unroll
    for (int k0 = 0; k0 < kD; k0 += 256) {
      float4 qa = *(const float4*)(q + k0 + lane * 4);
      float4 wa = *(const float4*)(w + k0 + lane * 4);
      s += qa.x * wa.x + qa.y * wa.y + qa.z * wa.z + qa.w * wa.w;
    }
#pragma unroll
    for (int off = 32; off > 0; off >>= 1) s += __shfl_down(s, off, 64);
    if (lane == 0) bias[gw] = b_enc[d] + s;
  } else if (blk < 2048 + 512) {
    // pack_w: Wbf[d][576] = [W_enc row | W_att row | zeros]
    int d = blk - 2048;
    for (int c = tid; c < kKP; c += 256) {
      float v = 0.f;
      if (c < kD)           v = W_enc[(size_t)d * kD + c];
      else if (c < kD + kC) v = W_att[(size_t)d * kC + (c - kD)];
      Wbf[(size_t)d * kKP + c] = f2bf(v);
    }
  } else if (blk < 2048 + 512 + 256) {
    // conv: channels -> Abf[b][t][512:576] (10 real + 54 zeros)
    int lin = blk - 2560;
    int b = lin >> 4, t0 = (lin & 15) * 256;
    for (int i = tid; i < kC * kKW; i += 256) wc[i] = W_conv[i];
    for (int i = tid; i < 256 + 2 * kFW; i += 256) {
      int p = t0 - kFW + i;
      ap[i] = (p >= 0 && p < kT) ? att_prev[(size_t)b * kT + p] : 0.f;
    }
    __syncthreads();
    float acc[kC];
#pragma unroll
    for (int c = 0; c < kC; ++c) acc[c] = 0.f;
    for (int j = 0; j < kKW; ++j) {
      float a = ap[tid + j];
#pragma unroll
      for (int c = 0; c < kC; ++c) acc[c] += a * wc[c * kKW + j];
    }
    unsigned ow[32];
#pragma unroll
    for (int i = 0; i < 5; ++i) ow[i] = pk2(acc[2 * i], acc[2 * i + 1]);
#pragma unroll
    for (int i = 5; i < 32; ++i) ow[i] = 0u;
    uint4* out = (uint4*)(Abf + ((size_t)b * kT + t0 + tid) * kKP + kD);
#pragma unroll
    for (int i = 0; i < 8; ++i)
      out[i] = make_uint4(ow[4 * i], ow[4 * i + 1], ow[4 * i + 2], ow[4 * i + 3]);
  } else {
    // convert: Abf[b][t][0:512] = bf16(value), 64 t-rows per block
    int lin = blk - 2816;
    int b = lin >> 6, t0 = (lin & 63) * 64;
    if (t0 >= lens[b]) return;
    const float* src = value + ((size_t)b * kT + t0) * kD;
    short* dst = Abf + ((size_t)b * kT + t0) * kKP;
#pragma unroll
    for (int i = 0; i < 16; ++i) {
      int c = tid + i * 256;
      int row = c >> 6, col = (c & 63) * 8;
      float4 f0 = *(const float4*)(src + (size_t)row * kD + col);
      float4 f1 = *(const float4*)(src + (size_t)row * kD + col + 4);
      uint4 o;
      o.x = pk2(f0.x, f0.y); o.y = pk2(f0.z, f0.w);
      o.z = pk2(f1.x, f1.y); o.w = pk2(f1.z, f1.w);
      *(uint4*)(dst + (size_t)row * kKP + col) = o;
    }
  }
}

// e_kernel: pure bf16 MFMA GEMM, 128x128 tile, BK=64 (9 K-steps), glds staging,
// XOR chunk-swizzle chunk' = chunk ^ (row&7) (R3-verified family, 0-conflict).
__global__ __launch_bounds__(256) void e_kernel(
    const short* __restrict__ Abf, const short* __restrict__ Wbf,
    const float* __restrict__ bias, const float* __restrict__ w_g,
    const int* __restrict__ lens, float* __restrict__ e_part) {
  __shared__ short As[128 * 64];   // 16 KB
  __shared__ short Bs[128 * 64];   // 16 KB

  int tid = threadIdx.x;
  // XCD-balanced swizzle: m-tiles round-robin over XCDs (mask-uniform), the
  // 4 n-blocks of one m-tile stay on one XCD (L2 A-reuse).
  int L    = blockIdx.x;
  int xcd  = L & 7;
  int slot = L >> 3;
  int bn   = slot & 3;
  int mt   = (slot >> 2) * 8 + xcd;    // 0..511
  int b  = mt >> 5;
  int t0 = (mt & 31) * 128;
  if (t0 >= lens[b]) return;           // masked tile: partials never read
  int n0 = bn * 128;

  int w    = tid >> 6;
  int lane = tid & 63;
  int nl   = lane & 15;
  int quad = lane >> 4;
  int wm = w >> 1, wn = w & 1;

  // staging: lane l deposits dest chunk (l&7) of dest row base+(l>>3);
  // source chunk kc = (l&7)^(l>>3) makes the deposit land swizzled.
  int r8 = lane >> 3;
  int kc = (lane & 7) ^ r8;
  const short* asrc = Abf + ((size_t)(b * kT + t0) + w * 32 + r8) * kKP + kc * 8;
  const short* bsrc = Wbf + (size_t)(n0 + w * 32 + r8) * kKP + kc * 8;
  short* adst = &As[(w * 32) * 64];
  short* bdst = &Bs[(w * 32) * 64];

  // frag read bases: row = (wm*64 + i*16 + nl), chunk' = (ks*4+quad) ^ (nl&7)
  int axr = nl & 7;
  const short* aBase = &As[(wm * 64 + nl) * 64];
  const short* bBase = &Bs[(wn * 64 + nl) * 64];
  int co0 = ((0 * 4 + quad) ^ axr) * 8;   // ks=0 chunk offset (shorts)
  int co1 = ((1 * 4 + quad) ^ axr) * 8;   // ks=1

  float4_t acc[4][4] = {};

  for (int kk = 0; kk < 9; ++kk) {
    int ko = kk * 64;
    __syncthreads();                   // prior frag reads done; LDS writable
#pragma unroll
    for (int j = 0; j < 4; ++j) {
      glds16(asrc + ko + (size_t)(j * 8) * kKP, adst + j * 8 * 64);
      glds16(bsrc + ko + (size_t)(j * 8) * kKP, bdst + j * 8 * 64);
    }
    __syncthreads();                   // drains glds deposits
#pragma unroll
    for (int ks = 0; ks < 2; ++ks) {
      int co = ks ? co1 : co0;
      short8_t a_frag[4], b_frag[4];
#pragma unroll
      for (int i = 0; i < 4; ++i) a_frag[i] = *(const short8_t*)(aBase + i * 1024 + co);
#pragma unroll
      for (int j = 0; j < 4; ++j) b_frag[j] = *(const short8_t*)(bBase + j * 1024 + co);
#pragma unroll
      for (int i = 0; i < 4; ++i)
#pragma unroll
        for (int j = 0; j < 4; ++j)
          acc[i][j] = __builtin_amdgcn_mfma_f32_16x16x32_bf16(
              a_frag[i], b_frag[j], acc[i][j], 0, 0, 0);
    }
  }

  // epilogue: partial e[t] = sum_d wg[d]*tanh(acc + bias[b,d]); 8 partials/(b,t)
  float bias_r[4], wg_r[4];
#pragma unroll
  for (int j = 0; j < 4; ++j) {
    int d = n0 + wn * 64 + j * 16 + nl;
    bias_r[j] = bias[b * kD + d];
    wg_r[j]   = w_g[d];
  }
  int p = wn * 4 + bn;
  float* ep = e_part + ((size_t)p * kB + b) * kT + t0 + wm * 64;
#pragma unroll
  for (int i = 0; i < 4; ++i) {
#pragma unroll
    for (int r = 0; r < 4; ++r) {
      float s = 0.f;
#pragma unroll
      for (int j = 0; j < 4; ++j)
        s += wg_r[j] * tanh_fast(acc[i][j][r] + bias_r[j]);
      s += __shfl_xor(s, 1, 64);
      s += __shfl_xor(s, 2, 64);
      s += __shfl_xor(s, 4, 64);
      s += __shfl_xor(s, 8, 64);
      if (nl == 0) ep[i * 16 + quad * 4 + r] = s;
    }
  }
}

// softmax stage 1: 128 blocks (b, 512-t chunk): combine 8 partials -> eb,
// chunk max + chunk sum-of-exp (local base) -> stats
__global__ void softmax1_kernel(const float* __restrict__ e_part,
                                const int* __restrict__ lens,
                                float* __restrict__ eb,
                                float* __restrict__ stats) {
  __shared__ float sred[256];
  int b = blockIdx.x >> 3, ch = blockIdx.x & 7;
  int tid = threadIdx.x;
  int len = lens[b];
  int base = ch * 512;
  const float* ep = e_part + (size_t)b * kT + base;
  float v[2];
  float m = -3.0e38f;
#pragma unroll
  for (int i = 0; i < 2; ++i) {
    int t = tid + i * 256;
    if (base + t < len) {
      float s = 0.f;
#pragma unroll
      for (int p = 0; p < 8; ++p) s += ep[(size_t)p * kB * kT + t];
      eb[(size_t)b * kT + base + t] = s;
      v[i] = s;
      m = fmaxf(m, s);
    } else {
      v[i] = -3.0e38f;
    }
  }
  sred[tid] = m; __syncthreads();
  for (int s = 128; s > 0; s >>= 1) {
    if (tid < s) sred[tid] = fmaxf(sred[tid], sred[tid + s]);
    __syncthreads();
  }
  m = sred[0]; __syncthreads();
  float l = 0.f;
#pragma unroll
  for (int i = 0; i < 2; ++i)
    if (v[i] > -1.0e38f) l += __expf(2.0f * (v[i] - m));
  sred[tid] = l; __syncthreads();
  for (int s = 128; s > 0; s >>= 1) {
    if (tid < s) sred[tid] += sred[tid + s];
    __syncthreads();
  }
  if (tid == 0) {
    stats[(b * 8 + ch) * 2]     = m;
    stats[(b * 8 + ch) * 2 + 1] = sred[0];
  }
}

// softmax stage 2: 16 blocks: combine chunk stats, write att; also zero ctx
__global__ void softmax2_kernel(const float* __restrict__ eb,
                                const float* __restrict__ stats,
                                const int* __restrict__ lens,
                                float* __restrict__ att,
                                float* __restrict__ ctx) {
  int b = blockIdx.x, tid = threadIdx.x;
  int len = lens[b];
  ctx[b * kD + tid * 2]     = 0.f;   // init for context atomics
  ctx[b * kD + tid * 2 + 1] = 0.f;
  float M = -3.0e38f;
#pragma unroll
  for (int p = 0; p < 8; ++p) M = fmaxf(M, stats[(b * 8 + p) * 2]);
  float L = 0.f;
#pragma unroll
  for (int p = 0; p < 8; ++p) {
    float mc = stats[(b * 8 + p) * 2], lc = stats[(b * 8 + p) * 2 + 1];
    if (lc > 0.f) L += lc * __expf(2.0f * (mc - M));
  }
  float inv = 1.0f / L;
  const float* e = eb + (size_t)b * kT;
  float* a = att + (size_t)b * kT;
#pragma unroll
  for (int i = 0; i < 16; ++i) {
    int t = tid + i * 256;
    a[t] = (t < len) ? __expf(2.0f * (e[t] - M)) * inv : 0.0f;
  }
}

// context[b,d] = sum_t bf16(value)[b,t,d]*att[b,t]  (reads Abf)
__global__ void context_kernel(const short* __restrict__ Abf,
                               const float* __restrict__ att,
                               const int* __restrict__ lens,
                               float* __restrict__ ctx) {
  __shared__ float red[4][kD];
  int b = blockIdx.y;
  int len = lens[b];
  int t0 = blockIdx.x * 128;
  if (t0 >= len) return;
  int w = threadIdx.x >> 6, lane = threadIdx.x & 63;
  int tb = t0 + w * 32;
  int tmax = min(32, len - tb);
  float a[8] = {0.f, 0.f, 0.f, 0.f, 0.f, 0.f, 0.f, 0.f};
  const short* vp = Abf + ((size_t)b * kT + tb) * kKP + lane * 8;
  const float* ap = att + (size_t)b * kT + tb;
  for (int t = 0; t < tmax; ++t) {
    float wt = ap[t];
    short8_t v = *(const short8_t*)(vp + (size_t)t * kKP);
#pragma unroll
    for (int i = 0; i < 8; ++i) a[i] += wt * bf2f(v[i]);
  }
#pragma unroll
  for (int i = 0; i < 8; ++i) red[w][lane * 8 + i] = a[i];
  __syncthreads();
  int tid = threadIdx.x;
  for (int col = tid; col < kD; col += 256) {
    float s = red[0][col] + red[1][col] + red[2][col] + red[3][col];
    atomicAdd(&ctx[b * kD + col], s);
  }
}

extern "C" void kernel_launch(void* const* d_in, const int* in_sizes, int n_in,
                              void* d_out, int out_size, void* d_ws, size_t ws_size,
                              hipStream_t stream) {
  const float* value    = (const float*)d_in[0];
  const float* query    = (const float*)d_in[1];
  const int*   lens     = (const int*)  d_in[2];
  const float* att_prev = (const float*)d_in[3];
  const float* W_enc    = (const float*)d_in[4];
  const float* b_enc    = (const float*)d_in[5];
  const float* W_dec    = (const float*)d_in[6];
  const float* W_att    = (const float*)d_in[7];
  const float* W_conv   = (const float*)d_in[8];
  const float* w_g      = (const float*)d_in[9];
  // d_in[10] = b_g : unused (softmax shift-invariant)

  float* ws     = (float*)d_ws;
  float* e_part = ws;                                      // 8*kB*kT   (2 MB)
  float* eb     = e_part + (size_t)8 * kB * kT;            // kB*kT     (256 KB)
  float* stats  = eb + (size_t)kB * kT;                    // 256 floats
  float* bias   = stats + 256;                             // kB*kD     (32 KB)
  short* Wbf    = (short*)(bias + (size_t)kB * kD);        // kD*kKP    (589 KB)
  short* Abf    = Wbf + (size_t)kD * kKP;                  // kB*kT*kKP (75.5 MB)
  float* ctx = (float*)d_out;
  float* att = ctx + (size_t)kB * kD;

  prep_kernel<<<3840, 256, 0, stream>>>(query, W_dec, b_enc, bias,
                                        W_enc, W_att, Wbf,
                                        att_prev, W_conv, value, lens, Abf);
  e_kernel<<<2048, 256, 0, stream>>>(Abf, Wbf, bias, w_g, lens, e_part);
  softmax1_kernel<<<kB * 8, 256, 0, stream>>>(e_part, lens, eb, stats);
  softmax2_kernel<<<kB, 256, 0, stream>>>(eb, stats, lens, att, (float*)d_out);
  context_kernel<<<dim3(kT / 128, kB), 256, 0, stream>>>(Abf, att, lens, ctx);
}

// Round 6
// 295.077 us; speedup vs baseline: 1.1819x; 1.0018x over previous
//
#include <hip/hip_runtime.h>
#include <hip/hip_bf16.h>

constexpr int kB  = 16;
constexpr int kT  = 4096;
constexpr int kD  = 512;
constexpr int kC  = 10;
constexpr int kFW = 100;
constexpr int kKW = 2 * kFW + 1;   // 201
constexpr int kKP = 544;           // GEMM K: 512 (W_enc) + 10 (W_att) + 22 zeros

typedef __attribute__((ext_vector_type(8))) short short8_t;  // 8 bf16 (4 VGPRs)
typedef __attribute__((ext_vector_type(4))) float float4_t;  // MFMA acc

__device__ __forceinline__ float tanh_fast(float x) {
  float ax = fabsf(x);
  float z  = __expf(-2.0f * ax);
  float r  = (1.0f - z) / (1.0f + z);
  return copysignf(r, x);
}

__device__ __forceinline__ short f2bf(float x) {  // RNE f32->bf16 (scalar)
  unsigned u = __float_as_uint(x);
  u += 0x7fffu + ((u >> 16) & 1u);
  return (short)(u >> 16);
}

__device__ __forceinline__ unsigned pk2(float lo, float hi) {  // packed cvt
  __hip_bfloat162 h = __float22bfloat162_rn(make_float2(lo, hi));
  union { __hip_bfloat162 h2; unsigned u; } cv; cv.h2 = h; return cv.u;
}

__device__ __forceinline__ float bf2f(short s) {
  return __uint_as_float(((unsigned)(unsigned short)s) << 16);
}

__device__ __forceinline__ void glds16(const void* g, void* l) {
  __builtin_amdgcn_global_load_lds(
      (const __attribute__((address_space(1))) void*)g,
      (__attribute__((address_space(3))) void*)l, 16, 0, 0);
}

// ---- fused prep: dec_bias | pack_w | conv | convert (independent block ranges)
__global__ __launch_bounds__(256) void prep_kernel(
    const float* __restrict__ query, const float* __restrict__ W_dec,
    const float* __restrict__ b_enc, float* __restrict__ bias,
    const float* __restrict__ W_enc, const float* __restrict__ W_att,
    short* __restrict__ Wbf,
    const float* __restrict__ att_prev, const float* __restrict__ W_conv,
    const float* __restrict__ value, const int* __restrict__ lens,
    short* __restrict__ Abf) {
  __shared__ float ap[256 + 2 * kFW];
  __shared__ float wc[kC * kKW];
  int blk = blockIdx.x;
  int tid = threadIdx.x;

  if (blk < 2048) {
    // dec_bias: bias[b,d] = b_enc[d] + query[b,:] . W_dec[d,:]
    int gw   = (blk * 256 + tid) >> 6;
    int lane = tid & 63;
    int b = gw >> 9, d = gw & (kD - 1);
    const float* q = query + (size_t)b * kD;
    const float* w = W_dec + (size_t)d * kD;
    float s = 0.f;
#pragma unroll
    for (int k0 = 0; k0 < kD; k0 += 256) {
      float4 qa = *(const float4*)(q + k0 + lane * 4);
      float4 wa = *(const float4*)(w + k0 + lane * 4);
      s += qa.x * wa.x + qa.y * wa.y + qa.z * wa.z + qa.w * wa.w;
    }
#pragma unroll
    for (int off = 32; off > 0; off >>= 1) s += __shfl_down(s, off, 64);
    if (lane == 0) bias[gw] = b_enc[d] + s;
  } else if (blk < 2048 + 512) {
    // pack_w: Wbf[d][544] = [W_enc row | W_att row | zeros]
    int d = blk - 2048;
    for (int c = tid; c < kKP; c += 256) {
      float v = 0.f;
      if (c < kD)           v = W_enc[(size_t)d * kD + c];
      else if (c < kD + kC) v = W_att[(size_t)d * kC + (c - kD)];
      Wbf[(size_t)d * kKP + c] = f2bf(v);
    }
  } else if (blk < 2048 + 512 + 256) {
    // conv: channels -> Abf[b][t][512:544] (10 real + 22 zeros)
    int lin = blk - 2560;
    int b = lin >> 4, t0 = (lin & 15) * 256;
    for (int i = tid; i < kC * kKW; i += 256) wc[i] = W_conv[i];
    for (int i = tid; i < 256 + 2 * kFW; i += 256) {
      int p = t0 - kFW + i;
      ap[i] = (p >= 0 && p < kT) ? att_prev[(size_t)b * kT + p] : 0.f;
    }
    __syncthreads();
    float acc[kC];
#pragma unroll
    for (int c = 0; c < kC; ++c) acc[c] = 0.f;
    for (int j = 0; j < kKW; ++j) {
      float a = ap[tid + j];
#pragma unroll
      for (int c = 0; c < kC; ++c) acc[c] += a * wc[c * kKW + j];
    }
    unsigned ow[16];
#pragma unroll
    for (int i = 0; i < 5; ++i) ow[i] = pk2(acc[2 * i], acc[2 * i + 1]);
#pragma unroll
    for (int i = 5; i < 16; ++i) ow[i] = 0u;
    uint4* out = (uint4*)(Abf + ((size_t)b * kT + t0 + tid) * kKP + kD);
#pragma unroll
    for (int i = 0; i < 4; ++i)
      out[i] = make_uint4(ow[4 * i], ow[4 * i + 1], ow[4 * i + 2], ow[4 * i + 3]);
  } else {
    // convert: Abf[b][t][0:512] = bf16(value), 64 t-rows per block
    int lin = blk - 2816;
    int b = lin >> 6, t0 = (lin & 63) * 64;
    if (t0 >= lens[b]) return;
    const float* src = value + ((size_t)b * kT + t0) * kD;
    short* dst = Abf + ((size_t)b * kT + t0) * kKP;
#pragma unroll
    for (int i = 0; i < 16; ++i) {
      int c = tid + i * 256;
      int row = c >> 6, col = (c & 63) * 8;
      float4 f0 = *(const float4*)(src + (size_t)row * kD + col);
      float4 f1 = *(const float4*)(src + (size_t)row * kD + col + 4);
      uint4 o;
      o.x = pk2(f0.x, f0.y); o.y = pk2(f0.z, f0.w);
      o.z = pk2(f1.x, f1.y); o.w = pk2(f1.z, f1.w);
      *(uint4*)(dst + (size_t)row * kKP + col) = o;
    }
  }
}

// e_kernel: pure bf16 MFMA GEMM, 128x128 tile, 8xBK64 + BK32 tail (K=544),
// glds staging, XOR chunk-swizzle (0-conflict main loop; tail 2-way = free).
__global__ __launch_bounds__(256, 4) void e_kernel(
    const short* __restrict__ Abf, const short* __restrict__ Wbf,
    const float* __restrict__ bias, const float* __restrict__ w_g,
    const int* __restrict__ lens, float* __restrict__ e_part) {
  __shared__ short As[128 * 64];   // 16 KB (tail reuses first 8 KB as [128][32])
  __shared__ short Bs[128 * 64];   // 16 KB

  int tid = threadIdx.x;
  // XCD-balanced swizzle: m-tiles round-robin over XCDs; the 4 n-blocks of one
  // m-tile stay on one XCD (L2 A-reuse).
  int L    = blockIdx.x;
  int xcd  = L & 7;
  int slot = L >> 3;
  int bn   = slot & 3;
  int mt   = (slot >> 2) * 8 + xcd;    // 0..511
  int b  = mt >> 5;
  int t0 = (mt & 31) * 128;
  if (t0 >= lens[b]) return;           // masked tile: partials never read
  int n0 = bn * 128;

  int w    = tid >> 6;
  int lane = tid & 63;
  int nl   = lane & 15;
  int quad = lane >> 4;
  int wm = w >> 1, wn = w & 1;

  // main staging: lane l -> dest row base+(l>>3), dest chunk (l&7);
  // source chunk kc = (l&7)^(l>>3) makes the deposit land swizzled.
  int r8 = lane >> 3;
  int kc = (lane & 7) ^ r8;
  const short* asrc = Abf + ((size_t)(b * kT + t0) + w * 32 + r8) * kKP + kc * 8;
  const short* bsrc = Wbf + (size_t)(n0 + w * 32 + r8) * kKP + kc * 8;
  short* adst = &As[(w * 32) * 64];
  short* bdst = &Bs[(w * 32) * 64];

  // main frag reads: row stride 64, chunk' = (ks*4+quad) ^ (nl&7)
  int axr = nl & 7;
  const short* aBase = &As[(wm * 64 + nl) * 64];
  const short* bBase = &Bs[(wn * 64 + nl) * 64];
  int co0 = ((0 * 4 + quad) ^ axr) * 8;
  int co1 = ((1 * 4 + quad) ^ axr) * 8;

  float4_t acc[4][4] = {};

  for (int kk = 0; kk < 8; ++kk) {
    int ko = kk * 64;
    __syncthreads();                   // prior frag reads done; LDS writable
#pragma unroll
    for (int j = 0; j < 4; ++j) {
      glds16(asrc + ko + (size_t)(j * 8) * kKP, adst + j * 8 * 64);
      glds16(bsrc + ko + (size_t)(j * 8) * kKP, bdst + j * 8 * 64);
    }
    __syncthreads();                   // drains glds deposits
#pragma unroll
    for (int ks = 0; ks < 2; ++ks) {
      int co = ks ? co1 : co0;
      short8_t a_frag[4], b_frag[4];
#pragma unroll
      for (int i = 0; i < 4; ++i) a_frag[i] = *(const short8_t*)(aBase + i * 1024 + co);
#pragma unroll
      for (int j = 0; j < 4; ++j) b_frag[j] = *(const short8_t*)(bBase + j * 1024 + co);
#pragma unroll
      for (int i = 0; i < 4; ++i)
#pragma unroll
        for (int j = 0; j < 4; ++j)
          acc[i][j] = __builtin_amdgcn_mfma_f32_16x16x32_bf16(
              a_frag[i], b_frag[j], acc[i][j], 0, 0, 0);
    }
  }

  // tail: k 512..543 (BK=32), contiguous [128][32] LDS view, mod-4 swizzle
  {
    __syncthreads();
    int r4  = lane >> 2;                       // 0..15
    int kc4 = (lane & 3) ^ (r4 & 3);
    const short* asrcT = Abf + ((size_t)(b * kT + t0) + w * 32 + r4) * kKP + 512 + kc4 * 8;
    const short* bsrcT = Wbf + (size_t)(n0 + w * 32 + r4) * kKP + 512 + kc4 * 8;
    short* adstT = &As[(w * 32) * 32];
    short* bdstT = &Bs[(w * 32) * 32];
    glds16(asrcT,                adstT);
    glds16(asrcT + 16 * kKP,     adstT + 16 * 32);
    glds16(bsrcT,                bdstT);
    glds16(bsrcT + 16 * kKP,     bdstT + 16 * 32);
    __syncthreads();
    int coT = (quad ^ (nl & 3)) * 8;
    const short* aBT = &As[(wm * 64 + nl) * 32];
    const short* bBT = &Bs[(wn * 64 + nl) * 32];
    short8_t a_frag[4], b_frag[4];
#pragma unroll
    for (int i = 0; i < 4; ++i) a_frag[i] = *(const short8_t*)(aBT + i * 512 + coT);
#pragma unroll
    for (int j = 0; j < 4; ++j) b_frag[j] = *(const short8_t*)(bBT + j * 512 + coT);
#pragma unroll
    for (int i = 0; i < 4; ++i)
#pragma unroll
      for (int j = 0; j < 4; ++j)
        acc[i][j] = __builtin_amdgcn_mfma_f32_16x16x32_bf16(
            a_frag[i], b_frag[j], acc[i][j], 0, 0, 0);
  }

  // epilogue: partial e[t] = sum_d wg[d]*tanh(acc + bias[b,d]); 8 partials/(b,t)
  float bias_r[4], wg_r[4];
#pragma unroll
  for (int j = 0; j < 4; ++j) {
    int d = n0 + wn * 64 + j * 16 + nl;
    bias_r[j] = bias[b * kD + d];
    wg_r[j]   = w_g[d];
  }
  int p = wn * 4 + bn;
  float* ep = e_part + ((size_t)p * kB + b) * kT + t0 + wm * 64;
#pragma unroll
  for (int i = 0; i < 4; ++i) {
#pragma unroll
    for (int r = 0; r < 4; ++r) {
      float s = 0.f;
#pragma unroll
      for (int j = 0; j < 4; ++j)
        s += wg_r[j] * tanh_fast(acc[i][j][r] + bias_r[j]);
      s += __shfl_xor(s, 1, 64);
      s += __shfl_xor(s, 2, 64);
      s += __shfl_xor(s, 4, 64);
      s += __shfl_xor(s, 8, 64);
      if (nl == 0) ep[i * 16 + quad * 4 + r] = s;
    }
  }
}

// softmax stage 1: 128 blocks (b, 512-t chunk): combine 8 partials -> eb,
// chunk max + chunk sum-of-exp -> stats; ch==0 blocks also zero ctx.
__global__ void softmax1_kernel(const float* __restrict__ e_part,
                                const int* __restrict__ lens,
                                float* __restrict__ eb,
                                float* __restrict__ stats,
                                float* __restrict__ ctx) {
  __shared__ float sred[256];
  int b = blockIdx.x >> 3, ch = blockIdx.x & 7;
  int tid = threadIdx.x;
  int len = lens[b];
  if (ch == 0) {                        // zero context accumulators
    ctx[b * kD + tid]       = 0.f;
    ctx[b * kD + 256 + tid] = 0.f;
  }
  int base = ch * 512;
  const float* ep = e_part + (size_t)b * kT + base;
  float v[2];
  float m = -3.0e38f;
#pragma unroll
  for (int i = 0; i < 2; ++i) {
    int t = tid + i * 256;
    if (base + t < len) {
      float s = 0.f;
#pragma unroll
      for (int p = 0; p < 8; ++p) s += ep[(size_t)p * kB * kT + t];
      eb[(size_t)b * kT + base + t] = s;
      v[i] = s;
      m = fmaxf(m, s);
    } else {
      v[i] = -3.0e38f;
    }
  }
  sred[tid] = m; __syncthreads();
  for (int s = 128; s > 0; s >>= 1) {
    if (tid < s) sred[tid] = fmaxf(sred[tid], sred[tid + s]);
    __syncthreads();
  }
  m = sred[0]; __syncthreads();
  float l = 0.f;
#pragma unroll
  for (int i = 0; i < 2; ++i)
    if (v[i] > -1.0e38f) l += __expf(2.0f * (v[i] - m));
  sred[tid] = l; __syncthreads();
  for (int s = 128; s > 0; s >>= 1) {
    if (tid < s) sred[tid] += sred[tid + s];
    __syncthreads();
  }
  if (tid == 0) {
    stats[(b * 8 + ch) * 2]     = m;
    stats[(b * 8 + ch) * 2 + 1] = sred[0];
  }
}

// fused att-write + context: finalize chunk stats per block (redundant, tiny),
// write att for this 128-t chunk, accumulate ctx via LDS + atomics.
__global__ void ctx_att_kernel(const float* __restrict__ eb,
                               const float* __restrict__ stats,
                               const int* __restrict__ lens,
                               const short* __restrict__ Abf,
                               float* __restrict__ att,
                               float* __restrict__ ctx) {
  __shared__ float red[4][kD];
  int b = blockIdx.y;
  int len = lens[b];
  int t0 = blockIdx.x * 128;
  int tid = threadIdx.x;
  float M = -3.0e38f;
#pragma unroll
  for (int p = 0; p < 8; ++p) M = fmaxf(M, stats[(b * 8 + p) * 2]);
  float Lsum = 0.f;
#pragma unroll
  for (int p = 0; p < 8; ++p) {
    float mc = stats[(b * 8 + p) * 2], lc = stats[(b * 8 + p) * 2 + 1];
    if (lc > 0.f) Lsum += lc * __expf(2.0f * (mc - M));
  }
  float inv = 1.0f / Lsum;
  const float* e = eb + (size_t)b * kT + t0;
  if (tid < 128) {
    int t = t0 + tid;
    att[(size_t)b * kT + t] = (t < len) ? __expf(2.0f * (e[tid] - M)) * inv : 0.0f;
  }
  if (t0 >= len) return;
  int w = tid >> 6, lane = tid & 63;
  int tb = w * 32;
  int tmax = min(32, len - t0 - tb);
  float a[8] = {0.f, 0.f, 0.f, 0.f, 0.f, 0.f, 0.f, 0.f};
  const short* vp = Abf + ((size_t)b * kT + t0 + tb) * kKP + lane * 8;
  for (int t = 0; t < tmax; ++t) {
    float wt = __expf(2.0f * (e[tb + t] - M)) * inv;
    short8_t v = *(const short8_t*)(vp + (size_t)t * kKP);
#pragma unroll
    for (int i = 0; i < 8; ++i) a[i] += wt * bf2f(v[i]);
  }
#pragma unroll
  for (int i = 0; i < 8; ++i) red[w][lane * 8 + i] = a[i];
  __syncthreads();
  for (int col = tid; col < kD; col += 256) {
    float s = red[0][col] + red[1][col] + red[2][col] + red[3][col];
    atomicAdd(&ctx[b * kD + col], s);
  }
}

extern "C" void kernel_launch(void* const* d_in, const int* in_sizes, int n_in,
                              void* d_out, int out_size, void* d_ws, size_t ws_size,
                              hipStream_t stream) {
  const float* value    = (const float*)d_in[0];
  const float* query    = (const float*)d_in[1];
  const int*   lens     = (const int*)  d_in[2];
  const float* att_prev = (const float*)d_in[3];
  const float* W_enc    = (const float*)d_in[4];
  const float* b_enc    = (const float*)d_in[5];
  const float* W_dec    = (const float*)d_in[6];
  const float* W_att    = (const float*)d_in[7];
  const float* W_conv   = (const float*)d_in[8];
  const float* w_g      = (const float*)d_in[9];
  // d_in[10] = b_g : unused (softmax shift-invariant)

  float* ws     = (float*)d_ws;
  float* e_part = ws;                                      // 8*kB*kT   (2 MB)
  float* eb     = e_part + (size_t)8 * kB * kT;            // kB*kT     (256 KB)
  float* stats  = eb + (size_t)kB * kT;                    // 256 floats
  float* bias   = stats + 256;                             // kB*kD     (32 KB)
  short* Wbf    = (short*)(bias + (size_t)kB * kD);        // kD*kKP    (557 KB)
  short* Abf    = Wbf + (size_t)kD * kKP;                  // kB*kT*kKP (71.3 MB)
  float* ctx = (float*)d_out;
  float* att = ctx + (size_t)kB * kD;

  prep_kernel<<<3840, 256, 0, stream>>>(query, W_dec, b_enc, bias,
                                        W_enc, W_att, Wbf,
                                        att_prev, W_conv, value, lens, Abf);
  e_kernel<<<2048, 256, 0, stream>>>(Abf, Wbf, bias, w_g, lens, e_part);
  softmax1_kernel<<<kB * 8, 256, 0, stream>>>(e_part, lens, eb, stats, ctx);
  ctx_att_kernel<<<dim3(kT / 128, kB), 256, 0, stream>>>(eb, stats, lens, Abf, att, ctx);
}